// Round 1
// baseline (12404.928 us; speedup 1.0000x reference)
//
#include <hip/hip_runtime.h>
#include <math.h>

#define NBLOCKS 256
#define NTHREADS 512
#define WPB 8                 // waves per block
#define HDIM 4096
#define NPAIR (HDIM/2)        // 2048 f16x2 pairs

typedef _Float16 f16x2  __attribute__((ext_vector_type(2)));
typedef _Float16 f16x16 __attribute__((ext_vector_type(16)));
typedef unsigned long long u64;

union UF { unsigned u; f16x2 h; };

__device__ __forceinline__ float dot2f(f16x2 a, f16x2 b, float c) {
  return __builtin_amdgcn_fdot2(a, b, c, false);   // v_dot2_f32_f16
}
__device__ __forceinline__ float sigmoidf_(float x) {
  return 1.0f / (1.0f + __expf(-x));
}
__device__ __forceinline__ float tanhf_(float x) {
  float a = fabsf(x);
  float t = __expf(-2.0f * a);
  float r = (1.0f - t) / (1.0f + t);
  return copysignf(r, x);
}
__device__ __forceinline__ void st64(u64* p, u64 v) {
  __hip_atomic_store(p, v, __ATOMIC_RELAXED, __HIP_MEMORY_SCOPE_AGENT);
}
__device__ __forceinline__ u64 ld64(const u64* p) {
  return __hip_atomic_load(p, __ATOMIC_RELAXED, __HIP_MEMORY_SCOPE_AGENT);
}

// ---- load one f16x16 chunk (8 f16x2 pairs, pair j at (const float2*)SRC + lane + 64*j) ----
#define LOAD_CHUNK(VAR, SRC, C) do {                                          \
  const float2* s_ = (const float2*)(SRC) + lane + 64 * ((C) * 8);            \
  float2 p0_ = s_[0];   float2 p1_ = s_[64];  float2 p2_ = s_[128];           \
  float2 p3_ = s_[192]; float2 p4_ = s_[256]; float2 p5_ = s_[320];           \
  float2 p6_ = s_[384]; float2 p7_ = s_[448];                                 \
  VAR = (f16x16){ (_Float16)p0_.x, (_Float16)p0_.y, (_Float16)p1_.x, (_Float16)p1_.y, \
                  (_Float16)p2_.x, (_Float16)p2_.y, (_Float16)p3_.x, (_Float16)p3_.y, \
                  (_Float16)p4_.x, (_Float16)p4_.y, (_Float16)p5_.x, (_Float16)p5_.y, \
                  (_Float16)p6_.x, (_Float16)p6_.y, (_Float16)p7_.x, (_Float16)p7_.y }; \
} while (0)

#define LOAD_ROW(K, GATE, IDX) do {                                           \
  const float* sr_ = W_hh + ((size_t)(GATE) * HDIM + (i0 + (IDX))) * HDIM;    \
  LOAD_CHUNK(w##K##_0, sr_, 0); LOAD_CHUNK(w##K##_1, sr_, 1);                 \
  LOAD_CHUNK(w##K##_2, sr_, 2); LOAD_CHUNK(w##K##_3, sr_, 3);                 \
} while (0)

#define PAIR(V, J) (__builtin_shufflevector((V), (V), 2 * (J), 2 * (J) + 1))

#define DOT8(K, C)                                                            \
  a##K = dot2f(PAIR(w##K##_##C, 0), hp0, a##K);                               \
  a##K = dot2f(PAIR(w##K##_##C, 1), hp1, a##K);                               \
  a##K = dot2f(PAIR(w##K##_##C, 2), hp2, a##K);                               \
  a##K = dot2f(PAIR(w##K##_##C, 3), hp3, a##K);                               \
  a##K = dot2f(PAIR(w##K##_##C, 4), hp4, a##K);                               \
  a##K = dot2f(PAIR(w##K##_##C, 5), hp5, a##K);                               \
  a##K = dot2f(PAIR(w##K##_##C, 6), hp6, a##K);                               \
  a##K = dot2f(PAIR(w##K##_##C, 7), hp7, a##K);

#define CHUNK_STEP(C) {                                                       \
  UF u0_, u1_, u2_, u3_, u4_, u5_, u6_, u7_;                                  \
  u0_.u = hb[lane + 64 * ((C) * 8 + 0)];                                      \
  u1_.u = hb[lane + 64 * ((C) * 8 + 1)];                                      \
  u2_.u = hb[lane + 64 * ((C) * 8 + 2)];                                      \
  u3_.u = hb[lane + 64 * ((C) * 8 + 3)];                                      \
  u4_.u = hb[lane + 64 * ((C) * 8 + 4)];                                      \
  u5_.u = hb[lane + 64 * ((C) * 8 + 5)];                                      \
  u6_.u = hb[lane + 64 * ((C) * 8 + 6)];                                      \
  u7_.u = hb[lane + 64 * ((C) * 8 + 7)];                                      \
  f16x2 hp0 = u0_.h, hp1 = u1_.h, hp2 = u2_.h, hp3 = u3_.h;                   \
  f16x2 hp4 = u4_.h, hp5 = u5_.h, hp6 = u6_.h, hp7 = u7_.h;                   \
  DOT8(0, C) DOT8(1, C) DOT8(2, C) DOT8(3, C) DOT8(4, C) DOT8(5, C)          \
}

#define GX_INIT(K, GATE, IDX) {                                               \
  const int row_ = (GATE) * HDIM + (i0 + (IDX));                              \
  const float* s_ = W_ih + (size_t)row_ * 400;                                \
  float acc_ = 0.0f;                                                          \
  for (int c = lane; c < 400; c += 64) acc_ += s_[c] * x_lds[c];              \
  _Pragma("unroll")                                                           \
  for (int o = 32; o; o >>= 1) acc_ += __shfl_xor(acc_, o, 64);               \
  acc_ += b_ih[row_];                                                         \
  if ((GATE) != 2) acc_ += b_hh[row_];                                        \
  gx##K = acc_;                                                               \
}

// Sticky-flag spin: each slot is re-read only until its tag matches, then
// written to LDS exactly once. Cuts steady-state coherent-point traffic from
// (full 16KB/block per round) to (stragglers only). Longer sleep before any
// arrival, short sleep once the burst has started.
#define SPIN_FILL(RD, EXP, HB) do {                                           \
  const int q0 = tid, q1 = tid + NTHREADS, q2 = tid + 2 * NTHREADS,           \
            q3 = tid + 3 * NTHREADS;                                          \
  bool d0 = false, d1 = false, d2 = false, d3 = false;                        \
  for (;;) {                                                                  \
    u64 v0 = 0, v1 = 0, v2 = 0, v3 = 0;                                       \
    if (!d0) v0 = ld64((RD) + q0);                                            \
    if (!d1) v1 = ld64((RD) + q1);                                            \
    if (!d2) v2 = ld64((RD) + q2);                                            \
    if (!d3) v3 = ld64((RD) + q3);                                            \
    if (!d0 && (unsigned)(v0 >> 32) == (EXP)) { (HB)[q0] = (unsigned)v0; d0 = true; } \
    if (!d1 && (unsigned)(v1 >> 32) == (EXP)) { (HB)[q1] = (unsigned)v1; d1 = true; } \
    if (!d2 && (unsigned)(v2 >> 32) == (EXP)) { (HB)[q2] = (unsigned)v2; d2 = true; } \
    if (!d3 && (unsigned)(v3 >> 32) == (EXP)) { (HB)[q3] = (unsigned)v3; d3 = true; } \
    if (d0 & d1 & d2 & d3) break;                                             \
    if (d0 | d1 | d2 | d3) __builtin_amdgcn_s_sleep(1);                       \
    else                   __builtin_amdgcn_s_sleep(2);                       \
  }                                                                           \
} while (0)

// 256 blocks x 512 threads, persistent. Wave g owns h indices {2g, 2g+1}.
// Weights live in 24 named f16x16 SSA values (192 VGPRs) — never an alloca.
__global__ __attribute__((amdgpu_flat_work_group_size(NTHREADS, NTHREADS),
                          amdgpu_waves_per_eu(2, 2)))
void gru_persistent(const float* __restrict__ start,
                    const float* __restrict__ enc_h,
                    const float* __restrict__ W_ih,
                    const float* __restrict__ W_hh,
                    const float* __restrict__ b_ih,
                    const float* __restrict__ b_hh,
                    const float* __restrict__ W_out,
                    const float* __restrict__ b_out,
                    float* __restrict__ out,
                    u64* __restrict__ ws,
                    int T)
{
  __shared__ unsigned h_lds[2][NPAIR];       // h_t as f16x2 pairs, double-buffered
  __shared__ unsigned wout_lds[2][NPAIR];    // this block's W_out rows, f16x2
  __shared__ float    x_lds[400];            // relu(start)

  const int tid  = threadIdx.x;
  const int b    = blockIdx.x;
  const int wave = tid >> 6;
  const int lane = tid & 63;
  const int g    = b * WPB + wave;           // global wave id, 0..2047
  const int i0   = 2 * g;

  u64* buf0 = ws;            // [NPAIR] tagged h pairs, even steps
  u64* buf1 = ws + NPAIR;    // [NPAIR] odd steps
  // tag for h_t is (t+1); ws 0xAA-poison never equals a valid tag.

  // ---- stage x = relu(start) and this block's W_out rows (f16) into LDS ----
  if (tid < 400) x_lds[tid] = fmaxf(start[tid], 0.0f);
  for (int s = 0; s < 2; ++s) {
    int row = 2 * b + s;
    if (row < 401) {
      for (int p = tid; p < NPAIR; p += NTHREADS) {
        float2 wv = *(const float2*)(W_out + (size_t)row * HDIM + 2 * p);
        UF u; u.h = (f16x2){(_Float16)wv.x, (_Float16)wv.y};
        wout_lds[s][p] = u.u;
      }
    }
  }
  __syncthreads();

  // ---- persistent W_hh fragment: 6 rows x 4 chunks of f16x16 ----
  f16x16 w0_0, w0_1, w0_2, w0_3;
  f16x16 w1_0, w1_1, w1_2, w1_3;
  f16x16 w2_0, w2_1, w2_2, w2_3;
  f16x16 w3_0, w3_1, w3_2, w3_3;
  f16x16 w4_0, w4_1, w4_2, w4_3;
  f16x16 w5_0, w5_1, w5_2, w5_3;
  LOAD_ROW(0, 0, 0); LOAD_ROW(1, 0, 1);   // r gate
  LOAD_ROW(2, 1, 0); LOAD_ROW(3, 1, 1);   // z gate
  LOAD_ROW(4, 2, 0); LOAD_ROW(5, 2, 1);   // n gate

  // ---- gx = W_ih @ relu(start) + b_ih (+ b_hh folded for r,z) ----
  float gx0, gx1, gx2, gx3, gx4, gx5;
  GX_INIT(0, 0, 0); GX_INIT(1, 0, 1);
  GX_INIT(2, 1, 0); GX_INIT(3, 1, 1);
  GX_INIT(4, 2, 0); GX_INIT(5, 2, 1);
  const float bhn0 = b_hh[2 * HDIM + i0];
  const float bhn1 = b_hh[2 * HDIM + i0 + 1];

  // ---- h carry (fp32, owner registers) ----
  float h0 = enc_h[i0], h1 = enc_h[i0 + 1];

  // publish h_0 (tag 1)
  if (lane == 0) {
    UF u; u.h = (f16x2){(_Float16)h0, (_Float16)h1};
    st64(&buf0[g], ((u64)1 << 32) | (u64)u.u);
  }

  // ---- main scan ----
  for (int t = 0; t < T; ++t) {
    u64* rd = (t & 1) ? buf1 : buf0;   // holds h_t, tag t+1
    u64* wr = (t & 1) ? buf0 : buf1;   // gets h_{t+1}, tag t+2
    const unsigned exp = (unsigned)(t + 1);
    unsigned* hb = h_lds[t & 1];

    // phase 1: sticky tagged spin + broadcast -> LDS (this IS the grid barrier)
    SPIN_FILL(rd, exp, hb);
    __syncthreads();

    // gh = W_hh @ h_t : 6 rows per wave
    float a0 = 0.f, a1 = 0.f, a2 = 0.f, a3 = 0.f, a4 = 0.f, a5 = 0.f;
    CHUNK_STEP(0); CHUNK_STEP(1); CHUNK_STEP(2); CHUNK_STEP(3);
    #pragma unroll
    for (int off = 32; off; off >>= 1) {
      a0 += __shfl_xor(a0, off, 64);
      a1 += __shfl_xor(a1, off, 64);
      a2 += __shfl_xor(a2, off, 64);
      a3 += __shfl_xor(a3, off, 64);
      a4 += __shfl_xor(a4, off, 64);
      a5 += __shfl_xor(a5, off, 64);
    }

    float r0 = sigmoidf_(gx0 + a0);
    float r1 = sigmoidf_(gx1 + a1);
    float z0 = sigmoidf_(gx2 + a2);
    float z1 = sigmoidf_(gx3 + a3);
    float n0 = tanhf_(gx4 + r0 * (a4 + bhn0));
    float n1 = tanhf_(gx5 + r1 * (a5 + bhn1));
    h0 = (1.0f - z0) * n0 + z0 * h0;
    h1 = (1.0f - z1) * n1 + z1 * h1;

    // publish h_{t+1} ASAP (tag t+2)
    if (lane == 0) {
      UF u; u.h = (f16x2){(_Float16)h0, (_Float16)h1};
      st64(&wr[g], ((u64)(unsigned)(t + 2) << 32) | (u64)u.u);
    }

    // output for step t-1 (uses h_t, still in hb) — hides in others' spin
    if (t > 0 && wave < 2) {
      int row = 2 * b + wave;
      if (row < 401) {
        float acc = 0.0f;
        #pragma unroll
        for (int j = 0; j < 32; ++j) {
          int p = lane + 64 * j;
          UF a, hh; a.u = wout_lds[wave][p]; hh.u = hb[p];
          acc = dot2f(a.h, hh.h, acc);
        }
        #pragma unroll
        for (int off = 32; off; off >>= 1) acc += __shfl_xor(acc, off, 64);
        if (lane == 0) {
          acc += b_out[row];
          if (row < 400) out[(size_t)(t - 1) * 400 + row] = tanhf_(acc);
          else           out[(size_t)400 * T + (t - 1)]   = sigmoidf_(acc);
        }
      }
    }
    // no trailing barrier: next iteration fills h_lds[(t+1)&1], and the reuse
    // of this buffer (t+2) is gated by the barrier at t+1.
  }

  // ---- final output flush: o_{T-1} = W_out @ h_T (tag T+1) ----
  {
    u64* rd = (T & 1) ? buf1 : buf0;
    const unsigned exp = (unsigned)(T + 1);
    unsigned* hb = h_lds[T & 1];
    SPIN_FILL(rd, exp, hb);
    __syncthreads();
    if (wave < 2) {
      int row = 2 * b + wave;
      if (row < 401) {
        float acc = 0.0f;
        #pragma unroll
        for (int j = 0; j < 32; ++j) {
          int p = lane + 64 * j;
          UF a, hh; a.u = wout_lds[wave][p]; hh.u = hb[p];
          acc = dot2f(a.h, hh.h, acc);
        }
        #pragma unroll
        for (int off = 32; off; off >>= 1) acc += __shfl_xor(acc, off, 64);
        if (lane == 0) {
          acc += b_out[row];
          if (row < 400) out[(size_t)(T - 1) * 400 + row] = tanhf_(acc);
          else           out[(size_t)400 * T + (T - 1)]   = sigmoidf_(acc);
        }
      }
    }
  }
}

extern "C" void kernel_launch(void* const* d_in, const int* in_sizes, int n_in,
                              void* d_out, int out_size, void* d_ws, size_t ws_size,
                              hipStream_t stream) {
  (void)in_sizes; (void)n_in; (void)ws_size;
  const float* start = (const float*)d_in[0];
  const float* enc_h = (const float*)d_in[1];
  const float* W_ih  = (const float*)d_in[2];
  const float* W_hh  = (const float*)d_in[3];
  const float* b_ih  = (const float*)d_in[4];
  const float* b_hh  = (const float*)d_in[5];
  const float* W_out = (const float*)d_in[6];
  const float* b_out = (const float*)d_in[7];
  float* out = (float*)d_out;
  u64* ws = (u64*)d_ws;

  int T = out_size / 401;   // outputs T*400 + stops T

  gru_persistent<<<NBLOCKS, NTHREADS, 0, stream>>>(
      start, enc_h, W_ih, W_hh, b_ih, b_hh, W_out, b_out, out, ws, T);
}

// Round 3
// 9454.131 us; speedup vs baseline: 1.3121x; 1.3121x over previous
//
#include <hip/hip_runtime.h>
#include <math.h>

#define NBLOCKS 256
#define NTHREADS 512
#define WPB 8                 // waves per block
#define HDIM 4096
#define NPAIR (HDIM/2)        // 2048 f16x2 pairs

typedef _Float16 f16x2  __attribute__((ext_vector_type(2)));
typedef _Float16 f16x16 __attribute__((ext_vector_type(16)));
typedef unsigned long long u64;

union UF { unsigned u; f16x2 h; };

__device__ __forceinline__ float dot2f(f16x2 a, f16x2 b, float c) {
  return __builtin_amdgcn_fdot2(a, b, c, false);   // v_dot2_f32_f16
}
__device__ __forceinline__ float sigmoidf_(float x) {
  return 1.0f / (1.0f + __expf(-x));
}
__device__ __forceinline__ float tanhf_(float x) {
  float a = fabsf(x);
  float t = __expf(-2.0f * a);
  float r = (1.0f - t) / (1.0f + t);
  return copysignf(r, x);
}
__device__ __forceinline__ void st64(u64* p, u64 v) {
  __hip_atomic_store(p, v, __ATOMIC_RELAXED, __HIP_MEMORY_SCOPE_AGENT);
}
__device__ __forceinline__ u64 ld64(const u64* p) {
  return __hip_atomic_load(p, __ATOMIC_RELAXED, __HIP_MEMORY_SCOPE_AGENT);
}

// ---- load one f16x16 chunk (8 f16x2 pairs, pair j at (const float2*)SRC + lane + 64*j) ----
#define LOAD_CHUNK(VAR, SRC, C) do {                                          \
  const float2* s_ = (const float2*)(SRC) + lane + 64 * ((C) * 8);            \
  float2 p0_ = s_[0];   float2 p1_ = s_[64];  float2 p2_ = s_[128];           \
  float2 p3_ = s_[192]; float2 p4_ = s_[256]; float2 p5_ = s_[320];           \
  float2 p6_ = s_[384]; float2 p7_ = s_[448];                                 \
  VAR = (f16x16){ (_Float16)p0_.x, (_Float16)p0_.y, (_Float16)p1_.x, (_Float16)p1_.y, \
                  (_Float16)p2_.x, (_Float16)p2_.y, (_Float16)p3_.x, (_Float16)p3_.y, \
                  (_Float16)p4_.x, (_Float16)p4_.y, (_Float16)p5_.x, (_Float16)p5_.y, \
                  (_Float16)p6_.x, (_Float16)p6_.y, (_Float16)p7_.x, (_Float16)p7_.y }; \
} while (0)

#define LOAD_ROW(K, GATE, IDX) do {                                           \
  const float* sr_ = W_hh + ((size_t)(GATE) * HDIM + (i0 + (IDX))) * HDIM;    \
  LOAD_CHUNK(w##K##_0, sr_, 0); LOAD_CHUNK(w##K##_1, sr_, 1);                 \
  LOAD_CHUNK(w##K##_2, sr_, 2); LOAD_CHUNK(w##K##_3, sr_, 3);                 \
} while (0)

#define PAIR(V, J) (__builtin_shufflevector((V), (V), 2 * (J), 2 * (J) + 1))

#define DOT8(K, C)                                                            \
  a##K = dot2f(PAIR(w##K##_##C, 0), hp0, a##K);                               \
  a##K = dot2f(PAIR(w##K##_##C, 1), hp1, a##K);                               \
  a##K = dot2f(PAIR(w##K##_##C, 2), hp2, a##K);                               \
  a##K = dot2f(PAIR(w##K##_##C, 3), hp3, a##K);                               \
  a##K = dot2f(PAIR(w##K##_##C, 4), hp4, a##K);                               \
  a##K = dot2f(PAIR(w##K##_##C, 5), hp5, a##K);                               \
  a##K = dot2f(PAIR(w##K##_##C, 6), hp6, a##K);                               \
  a##K = dot2f(PAIR(w##K##_##C, 7), hp7, a##K);

// reg rows only (0..3): r and z gates
#define CHUNK_STEP(C) {                                                       \
  UF u0_, u1_, u2_, u3_, u4_, u5_, u6_, u7_;                                  \
  u0_.u = h_lds[lane + 64 * ((C) * 8 + 0)];                                   \
  u1_.u = h_lds[lane + 64 * ((C) * 8 + 1)];                                   \
  u2_.u = h_lds[lane + 64 * ((C) * 8 + 2)];                                   \
  u3_.u = h_lds[lane + 64 * ((C) * 8 + 3)];                                   \
  u4_.u = h_lds[lane + 64 * ((C) * 8 + 4)];                                   \
  u5_.u = h_lds[lane + 64 * ((C) * 8 + 5)];                                   \
  u6_.u = h_lds[lane + 64 * ((C) * 8 + 6)];                                   \
  u7_.u = h_lds[lane + 64 * ((C) * 8 + 7)];                                   \
  f16x2 hp0 = u0_.h, hp1 = u1_.h, hp2 = u2_.h, hp3 = u3_.h;                   \
  f16x2 hp4 = u4_.h, hp5 = u5_.h, hp6 = u6_.h, hp7 = u7_.h;                   \
  DOT8(0, C) DOT8(1, C) DOT8(2, C) DOT8(3, C)                                 \
}

#define GX_INIT(K, GATE, IDX) {                                               \
  const int row_ = (GATE) * HDIM + (i0 + (IDX));                              \
  const float* s_ = W_ih + (size_t)row_ * 400;                                \
  float acc_ = 0.0f;                                                          \
  for (int c = lane; c < 400; c += 64) acc_ += s_[c] * x_lds[c];              \
  _Pragma("unroll")                                                           \
  for (int o = 32; o; o >>= 1) acc_ += __shfl_xor(acc_, o, 64);               \
  acc_ += b_ih[row_];                                                         \
  if ((GATE) != 2) acc_ += b_hh[row_];                                        \
  gx##K = acc_;                                                               \
}

// 256 blocks x 512 threads, persistent. Wave g owns h indices {2g, 2g+1}.
// r/z-gate weights (4 rows) live in 16 named f16x16 SSA values (128 VGPRs);
// n-gate weights (2 rows) live in LDS (128 KB/block) — total register demand
// ~190 <= 256 so nothing spills.
__global__ __attribute__((amdgpu_flat_work_group_size(NTHREADS, NTHREADS),
                          amdgpu_waves_per_eu(2, 2)))
void gru_persistent(const float* __restrict__ start,
                    const float* __restrict__ enc_h,
                    const float* __restrict__ W_ih,
                    const float* __restrict__ W_hh,
                    const float* __restrict__ b_ih,
                    const float* __restrict__ b_hh,
                    const float* __restrict__ W_out,
                    const float* __restrict__ b_out,
                    float* __restrict__ out,
                    u64* __restrict__ ws,
                    int T)
{
  __shared__ unsigned h_lds[NPAIR];            // h_t as f16x2 pairs       (8 KB)
  __shared__ unsigned wout_lds[2][NPAIR];      // block's W_out rows, f16x2 (16 KB)
  __shared__ unsigned w_lds[WPB * 2 * NPAIR];  // n-gate W_hh rows, f16x2  (128 KB)
  __shared__ float    x_lds[400];              // relu(start)              (1.6 KB)

  const int tid  = threadIdx.x;
  const int b    = blockIdx.x;
  const int wave = tid >> 6;
  const int lane = tid & 63;
  const int g    = b * WPB + wave;           // global wave id, 0..2047
  const int i0   = 2 * g;

  u64* buf0 = ws;            // [NPAIR] tagged h pairs, even steps
  u64* buf1 = ws + NPAIR;    // [NPAIR] odd steps
  // tag for h_t is (t+1); ws 0xAA-poison never equals a valid tag.

  // ---- stage x = relu(start) and this block's W_out rows (f16) into LDS ----
  if (tid < 400) x_lds[tid] = fmaxf(start[tid], 0.0f);
  for (int s = 0; s < 2; ++s) {
    int row = 2 * b + s;
    if (row < 401) {
      for (int p = tid; p < NPAIR; p += NTHREADS) {
        float2 wv = *(const float2*)(W_out + (size_t)row * HDIM + 2 * p);
        UF u; u.h = (f16x2){(_Float16)wv.x, (_Float16)wv.y};
        wout_lds[s][p] = u.u;
      }
    }
  }
  // ---- stage n-gate W_hh rows (2 per wave, 16 per block) as f16x2 into LDS ----
  for (int q = tid; q < WPB * 2 * NPAIR; q += NTHREADS) {
    const int lrow = q >> 11;            // 0..15 = wave*2 + r
    const int p    = q & (NPAIR - 1);
    const int wv   = lrow >> 1, rr = lrow & 1;
    const size_t grow = (size_t)2 * HDIM + 2 * (b * WPB + wv) + rr;
    const float2 wvv = *(const float2*)(W_hh + grow * HDIM + 2 * p);
    UF u; u.h = (f16x2){(_Float16)wvv.x, (_Float16)wvv.y};
    w_lds[q] = u.u;
  }
  __syncthreads();

  // ---- persistent W_hh fragment: 4 rows (r,z) x 4 chunks of f16x16 ----
  f16x16 w0_0, w0_1, w0_2, w0_3;
  f16x16 w1_0, w1_1, w1_2, w1_3;
  f16x16 w2_0, w2_1, w2_2, w2_3;
  f16x16 w3_0, w3_1, w3_2, w3_3;
  LOAD_ROW(0, 0, 0); LOAD_ROW(1, 0, 1);   // r gate
  LOAD_ROW(2, 1, 0); LOAD_ROW(3, 1, 1);   // z gate

  // ---- gx = W_ih @ relu(start) + b_ih (+ b_hh folded for r,z) ----
  float gx0, gx1, gx2, gx3, gx4, gx5;
  GX_INIT(0, 0, 0); GX_INIT(1, 0, 1);
  GX_INIT(2, 1, 0); GX_INIT(3, 1, 1);
  GX_INIT(4, 2, 0); GX_INIT(5, 2, 1);
  const float bhn0 = b_hh[2 * HDIM + i0];
  const float bhn1 = b_hh[2 * HDIM + i0 + 1];

  // ---- h carry (fp32, owner registers) ----
  float h0 = enc_h[i0], h1 = enc_h[i0 + 1];

  // publish h_0 (tag 1)
  if (lane == 0) {
    UF u; u.h = (f16x2){(_Float16)h0, (_Float16)h1};
    st64(&buf0[g], ((u64)1 << 32) | (u64)u.u);
  }

  const unsigned* wl4_ = w_lds + (wave * 2 + 0) * NPAIR;
  const unsigned* wl5_ = w_lds + (wave * 2 + 1) * NPAIR;

  // ---- main scan ----
  for (int t = 0; t < T; ++t) {
    u64* rd = (t & 1) ? buf1 : buf0;   // holds h_t, tag t+1
    u64* wr = (t & 1) ? buf0 : buf1;   // gets h_{t+1}, tag t+2
    const unsigned exp = (unsigned)(t + 1);

    // phase 1: tagged spin + broadcast -> LDS (this IS the grid barrier).
    // FROZEN: constant sleep(1); lanes that break are exec-masked (lane-sticky).
    {
      const int p0 = tid, p1 = tid + NTHREADS, p2 = tid + 2 * NTHREADS, p3 = tid + 3 * NTHREADS;
      u64 v0, v1, v2, v3;
      for (;;) {
        v0 = ld64(rd + p0); v1 = ld64(rd + p1);
        v2 = ld64(rd + p2); v3 = ld64(rd + p3);
        if ((unsigned)(v0 >> 32) == exp && (unsigned)(v1 >> 32) == exp &&
            (unsigned)(v2 >> 32) == exp && (unsigned)(v3 >> 32) == exp) break;
        __builtin_amdgcn_s_sleep(1);
      }
      h_lds[p0] = (unsigned)v0; h_lds[p1] = (unsigned)v1;
      h_lds[p2] = (unsigned)v2; h_lds[p3] = (unsigned)v3;
    }
    __syncthreads();

    // gh = W_hh @ h_t : rows 0..3 from registers
    float a0 = 0.f, a1 = 0.f, a2 = 0.f, a3 = 0.f, a4 = 0.f, a5 = 0.f;
    CHUNK_STEP(0); CHUNK_STEP(1); CHUNK_STEP(2); CHUNK_STEP(3);

    // rows 4,5 (n gate) from LDS: linear b128 pattern, conflict-free
    #pragma unroll
    for (int j = 0; j < 8; ++j) {
      const int p = 4 * lane + 256 * j;
      uint4 w4v = *(const uint4*)(wl4_ + p);
      uint4 w5v = *(const uint4*)(wl5_ + p);
      uint4 hv  = *(const uint4*)(h_lds + p);
      UF ww, hh;
      hh.u = hv.x; ww.u = w4v.x; a4 = dot2f(ww.h, hh.h, a4);
                   ww.u = w5v.x; a5 = dot2f(ww.h, hh.h, a5);
      hh.u = hv.y; ww.u = w4v.y; a4 = dot2f(ww.h, hh.h, a4);
                   ww.u = w5v.y; a5 = dot2f(ww.h, hh.h, a5);
      hh.u = hv.z; ww.u = w4v.z; a4 = dot2f(ww.h, hh.h, a4);
                   ww.u = w5v.z; a5 = dot2f(ww.h, hh.h, a5);
      hh.u = hv.w; ww.u = w4v.w; a4 = dot2f(ww.h, hh.h, a4);
                   ww.u = w5v.w; a5 = dot2f(ww.h, hh.h, a5);
    }

    #pragma unroll
    for (int off = 32; off; off >>= 1) {
      a0 += __shfl_xor(a0, off, 64);
      a1 += __shfl_xor(a1, off, 64);
      a2 += __shfl_xor(a2, off, 64);
      a3 += __shfl_xor(a3, off, 64);
      a4 += __shfl_xor(a4, off, 64);
      a5 += __shfl_xor(a5, off, 64);
    }

    float r0 = sigmoidf_(gx0 + a0);
    float r1 = sigmoidf_(gx1 + a1);
    float z0 = sigmoidf_(gx2 + a2);
    float z1 = sigmoidf_(gx3 + a3);
    float n0 = tanhf_(gx4 + r0 * (a4 + bhn0));
    float n1 = tanhf_(gx5 + r1 * (a5 + bhn1));
    h0 = (1.0f - z0) * n0 + z0 * h0;
    h1 = (1.0f - z1) * n1 + z1 * h1;

    // publish h_{t+1} ASAP (tag t+2)
    if (lane == 0) {
      UF u; u.h = (f16x2){(_Float16)h0, (_Float16)h1};
      st64(&wr[g], ((u64)(unsigned)(t + 2) << 32) | (u64)u.u);
    }

    // output for step t-1 (uses h_t, still in LDS) — hides in others' spin
    if (t > 0 && wave < 2) {
      int row = 2 * b + wave;
      if (row < 401) {
        float acc = 0.0f;
        #pragma unroll
        for (int j = 0; j < 32; ++j) {
          int p = lane + 64 * j;
          UF a, hh; a.u = wout_lds[wave][p]; hh.u = h_lds[p];
          acc = dot2f(a.h, hh.h, acc);
        }
        #pragma unroll
        for (int off = 32; off; off >>= 1) acc += __shfl_xor(acc, off, 64);
        if (lane == 0) {
          acc += b_out[row];
          if (row < 400) out[(size_t)(t - 1) * 400 + row] = tanhf_(acc);
          else           out[(size_t)400 * T + (t - 1)]   = sigmoidf_(acc);
        }
      }
    }
    __syncthreads();   // protect h_lds before next phase-1 overwrite
  }

  // ---- final output flush: o_{T-1} = W_out @ h_T (tag T+1) ----
  {
    u64* rd = (T & 1) ? buf1 : buf0;
    const unsigned exp = (unsigned)(T + 1);
    const int p0 = tid, p1 = tid + NTHREADS, p2 = tid + 2 * NTHREADS, p3 = tid + 3 * NTHREADS;
    u64 v0, v1, v2, v3;
    for (;;) {
      v0 = ld64(rd + p0); v1 = ld64(rd + p1);
      v2 = ld64(rd + p2); v3 = ld64(rd + p3);
      if ((unsigned)(v0 >> 32) == exp && (unsigned)(v1 >> 32) == exp &&
          (unsigned)(v2 >> 32) == exp && (unsigned)(v3 >> 32) == exp) break;
      __builtin_amdgcn_s_sleep(1);
    }
    h_lds[p0] = (unsigned)v0; h_lds[p1] = (unsigned)v1;
    h_lds[p2] = (unsigned)v2; h_lds[p3] = (unsigned)v3;
    __syncthreads();
    if (wave < 2) {
      int row = 2 * b + wave;
      if (row < 401) {
        float acc = 0.0f;
        #pragma unroll
        for (int j = 0; j < 32; ++j) {
          int p = lane + 64 * j;
          UF a, hh; a.u = wout_lds[wave][p]; hh.u = h_lds[p];
          acc = dot2f(a.h, hh.h, acc);
        }
        #pragma unroll
        for (int off = 32; off; off >>= 1) acc += __shfl_xor(acc, off, 64);
        if (lane == 0) {
          acc += b_out[row];
          if (row < 400) out[(size_t)(T - 1) * 400 + row] = tanhf_(acc);
          else           out[(size_t)400 * T + (T - 1)]   = sigmoidf_(acc);
        }
      }
    }
  }
}

extern "C" void kernel_launch(void* const* d_in, const int* in_sizes, int n_in,
                              void* d_out, int out_size, void* d_ws, size_t ws_size,
                              hipStream_t stream) {
  (void)in_sizes; (void)n_in; (void)ws_size;
  const float* start = (const float*)d_in[0];
  const float* enc_h = (const float*)d_in[1];
  const float* W_ih  = (const float*)d_in[2];
  const float* W_hh  = (const float*)d_in[3];
  const float* b_ih  = (const float*)d_in[4];
  const float* b_hh  = (const float*)d_in[5];
  const float* W_out = (const float*)d_in[6];
  const float* b_out = (const float*)d_in[7];
  float* out = (float*)d_out;
  u64* ws = (u64*)d_ws;

  int T = out_size / 401;   // outputs T*400 + stops T

  gru_persistent<<<NBLOCKS, NTHREADS, 0, stream>>>(
      start, enc_h, W_ih, W_hh, b_ih, b_hh, W_out, b_out, out, ws, T);
}